// Round 5
// baseline (201.537 us; speedup 1.0000x reference)
//
#include <hip/hip_runtime.h>

namespace {

constexpr int W_RES = 320, H_RES = 240, BS = 4, VD = 128, NS = 256;
constexpr float DENS_SCALE = 100.0f / 256.0f / 255.0f;  // u8 units -> ds
constexpr float TAU = 5e-4f;   // early-exit transmittance
constexpr long long VOX = (long long)VD * VD * VD;  // 2,097,152
constexpr int NTILE = (W_RES / 16) * (H_RES / 4) * BS;  // 20*60*4 = 4800
constexpr size_t CTR_OFF = (size_t)BS * VOX * 4;        // 33,554,432 B

// Transpose (B,4,D,H,W) fp32 -> (B,D,H,W) packed u8x4 {r,g,b,density}.
// Also zeroes the work-queue counter (thread 0).
__global__ void transpose_k(const float* __restrict__ vol, uint4* __restrict__ out,
                            unsigned* __restrict__ ctr) {
    long long tid = (long long)blockIdx.x * blockDim.x + threadIdx.x;
    if (tid == 0) *ctr = 0u;
    const long long nq = (long long)BS * VOX / 4;  // quads of voxels
    if (tid >= nq) return;
    int b = (int)(tid / (VOX / 4));
    long long r4 = (tid - (long long)b * (VOX / 4)) * 4;
    const float* vb = vol + (long long)b * 4 * VOX + r4;
    float4 R = *(const float4*)(vb);
    float4 G = *(const float4*)(vb + VOX);
    float4 Bc = *(const float4*)(vb + 2 * VOX);
    float4 Dn = *(const float4*)(vb + 3 * VOX);
    auto pk = [](float r, float g, float bl, float d) -> unsigned {
        unsigned ur = (unsigned)(r * 255.0f + 0.5f);
        unsigned ug = (unsigned)(g * 255.0f + 0.5f);
        unsigned ub = (unsigned)(bl * 255.0f + 0.5f);
        unsigned ud = (unsigned)(d * 255.0f + 0.5f);
        return ur | (ug << 8) | (ub << 16) | (ud << 24);
    };
    uint4 o;
    o.x = pk(R.x, G.x, Bc.x, Dn.x);
    o.y = pk(R.y, G.y, Bc.y, Dn.y);
    o.z = pk(R.z, G.z, Bc.z, Dn.z);
    o.w = pk(R.w, G.w, Bc.w, Dn.w);
    out[tid] = o;
}

struct St {
    unsigned p[8];
    float w[8];
};

struct Coord {
    int x0, y0, z0;
    float fx, fy, fz;
    bool fast;
};

__device__ __forceinline__ Coord mkc(float ix, float iy, float iz) {
    Coord c;
    float f;
    f = floorf(ix); c.fx = ix - f; c.x0 = (int)f;
    f = floorf(iy); c.fy = iy - f; c.y0 = (int)f;
    f = floorf(iz); c.fz = iz - f; c.z0 = (int)f;
    c.fast = ((unsigned)c.x0 < 127u) & ((unsigned)c.y0 < 127u) & ((unsigned)c.z0 < 127u);
    return c;
}

__device__ __forceinline__ void wts(const Coord& c, St& st, float mx0, float mx1,
                                    float my0, float my1, float mz0, float mz1) {
    float wx0 = (1.0f - c.fx) * mx0, wx1 = c.fx * mx1;
    float wy0 = (1.0f - c.fy) * my0, wy1 = c.fy * my1;
    float wz0 = (1.0f - c.fz) * mz0, wz1 = c.fz * mz1;
    float w00 = wz0 * wy0, w01 = wz0 * wy1, w10 = wz1 * wy0, w11 = wz1 * wy1;
    st.w[0] = w00 * wx0; st.w[1] = w00 * wx1;
    st.w[2] = w01 * wx0; st.w[3] = w01 * wx1;
    st.w[4] = w10 * wx0; st.w[5] = w10 * wx1;
    st.w[6] = w11 * wx0; st.w[7] = w11 * wx1;
}

__device__ __forceinline__ void stage_fast(const unsigned* __restrict__ vb,
                                           const Coord& c, St& st) {
    const unsigned* r0 = vb + ((c.z0 * VD + c.y0) * VD + c.x0);
    const unsigned* r1 = r0 + VD * VD;
    st.p[0] = r0[0];  st.p[1] = r0[1];
    st.p[2] = r0[VD]; st.p[3] = r0[VD + 1];
    st.p[4] = r1[0];  st.p[5] = r1[1];
    st.p[6] = r1[VD]; st.p[7] = r1[VD + 1];
    wts(c, st, 1, 1, 1, 1, 1, 1);
}

__device__ __forceinline__ void stage_safe(const unsigned* __restrict__ vb,
                                           const Coord& c, St& st) {
    int x0 = c.x0, y0 = c.y0, z0 = c.z0;
    float mx0 = ((unsigned)x0 < 128u) ? 1.0f : 0.0f;
    float mx1 = ((unsigned)(x0 + 1) < 128u) ? 1.0f : 0.0f;
    float my0 = ((unsigned)y0 < 128u) ? 1.0f : 0.0f;
    float my1 = ((unsigned)(y0 + 1) < 128u) ? 1.0f : 0.0f;
    float mz0 = ((unsigned)z0 < 128u) ? 1.0f : 0.0f;
    float mz1 = ((unsigned)(z0 + 1) < 128u) ? 1.0f : 0.0f;

    int xc0 = min(max(x0, 0), 127), xc1 = min(max(x0 + 1, 0), 127);
    int yc0 = min(max(y0, 0), 127), yc1 = min(max(y0 + 1, 0), 127);
    int zc0 = min(max(z0, 0), 127), zc1 = min(max(z0 + 1, 0), 127);

    int r00 = (zc0 * VD + yc0) * VD, r01 = (zc0 * VD + yc1) * VD;
    int r10 = (zc1 * VD + yc0) * VD, r11 = (zc1 * VD + yc1) * VD;

    st.p[0] = vb[r00 + xc0]; st.p[1] = vb[r00 + xc1];
    st.p[2] = vb[r01 + xc0]; st.p[3] = vb[r01 + xc1];
    st.p[4] = vb[r10 + xc0]; st.p[5] = vb[r10 + xc1];
    st.p[6] = vb[r11 + xc0]; st.p[7] = vb[r11 + xc1];

    wts(c, st, mx0, mx1, my0, my1, mz0, mz1);
}

__device__ __forceinline__ void consume(const St& st, float& T, float& wsum,
                                        float& aR, float& aG, float& aB) {
    float ar = 0, ag = 0, ab = 0, ad = 0;
#pragma unroll
    for (int i = 0; i < 8; ++i) {
        unsigned cv = st.p[i];
        float w = st.w[i];
        ar = fmaf(w, (float)(cv & 255u), ar);
        ag = fmaf(w, (float)((cv >> 8) & 255u), ag);
        ab = fmaf(w, (float)((cv >> 16) & 255u), ab);
        ad = fmaf(w, (float)(cv >> 24), ad);
    }
    float dsv = ad * DENS_SCALE;
    T *= (1.0f - dsv);
    float wgt = dsv * T;
    wsum += wgt;
    aR = fmaf(wgt, ar, aR);
    aG = fmaf(wgt, ag, aG);
    aB = fmaf(wgt, ab, aB);
}

__global__ void __launch_bounds__(64) raycast_k(const unsigned* __restrict__ vol,
                                                const float* __restrict__ tfm,
                                                float* __restrict__ out,
                                                unsigned* __restrict__ ctr) {
    constexpr int NPIX = W_RES * H_RES;
    const int lane = threadIdx.x;
    const float dZ = 2.0f / (float)(NS - 1);

    while (true) {
        unsigned n = 0;
        if (lane == 0) n = atomicAdd(ctr, 1u);
        n = (unsigned)__shfl((int)n, 0);
        if (n >= (unsigned)NTILE) return;

        // Decode tile: batches interleaved fastest; columns center-out (LPT:
        // in-box path length varies mainly with X for y-axis rotations).
        int b = n & 3;
        int k = n >> 2;          // 0..1199
        int cxr = k / 60;        // column rank 0..19 (center-out)
        int ryr = k - cxr * 60;  // row rank 0..59 (center-out)
        int tx = (cxr & 1) ? (9 - (cxr >> 1)) : (10 + (cxr >> 1));
        int ty = (ryr & 1) ? (29 - (ryr >> 1)) : (30 + (ryr >> 1));
        int x = tx * 16 + (lane & 15);
        int y = ty * 4 + (lane >> 4);

        float X = -1.0f + 2.0f * x / (float)(W_RES - 1);
        float Y = -1.0f + 2.0f * y / (float)(H_RES - 1);

        const float* M = tfm + b * 16;
        float bxc = M[0] * X + M[1] * Y + M[3];
        float byc = M[4] * X + M[5] * Y + M[7];
        float bzc = M[8] * X + M[9] * Y + M[11];
        float bwc = M[12] * X + M[13] * Y + M[15];
        float m02 = M[2], m12 = M[6], m22 = M[10], m32 = M[14];

        const unsigned* vb = vol + (long long)b * VOX;

        // Ray-box clip (exact when w row trivial; guarded for generality).
        bool w1 = (fabsf(bwc - 1.0f) < 1e-6f) && (fabsf(m32) < 1e-6f);
        float lo = 0.0f, hi = (float)(NS - 1);
        if (w1) {
            const float LIM = 1.0078125f + 1e-5f;
            auto clipAxis = [&](float bb, float mm) {
                float A = bb - mm;  // g(s) = A + B*s
                float Bq = mm * dZ;
                if (fabsf(Bq) < 1e-9f) {
                    if (fabsf(A) > LIM) { lo = 1.0f; hi = 0.0f; }
                } else {
                    float s1 = (-LIM - A) / Bq, s2 = (LIM - A) / Bq;
                    lo = fmaxf(lo, fminf(s1, s2));
                    hi = fminf(hi, fmaxf(s1, s2));
                }
            };
            clipAxis(bxc, m02);
            clipAxis(byc, m12);
            clipAxis(bzc, m22);
        }
        int s_start = max(0, (int)ceilf(lo - 1e-3f));
        int s_end = min(NS - 1, (int)floorf(hi + 1e-3f));

        int wsv = s_start, wev = s_end;
#pragma unroll
        for (int off = 1; off < 64; off <<= 1) {
            wsv = min(wsv, __shfl_xor(wsv, off));
            wev = max(wev, __shfl_xor(wev, off));
        }

        auto coords = [&](int s, float& ix, float& iy, float& iz) {
            float Z = fmaf((float)s, dZ, -1.0f);
            float gx = fmaf(m02, Z, bxc);
            float gy = fmaf(m12, Z, byc);
            float gz = fmaf(m22, Z, bzc);
            if (!w1) {
                float iw = 1.0f / fmaf(m32, Z, bwc);
                gx *= iw; gy *= iw; gz *= iw;
            }
            ix = fmaf(gx, 64.0f, 63.5f);
            iy = fmaf(gy, 64.0f, 63.5f);
            iz = fmaf(gz, 64.0f, 63.5f);
        };

        float T = 1.0f, wsum = 0.0f, aR = 0.0f, aG = 0.0f, aB = 0.0f;
        St S0, S1, S2, S3;

        for (int s = wsv; s <= wev; s += 4) {
            float ix, iy, iz;
            coords(s, ix, iy, iz);      Coord c0 = mkc(ix, iy, iz);
            coords(s + 1, ix, iy, iz);  Coord c1 = mkc(ix, iy, iz);
            coords(s + 2, ix, iy, iz);  Coord c2 = mkc(ix, iy, iz);
            coords(s + 3, ix, iy, iz);  Coord c3 = mkc(ix, iy, iz);
            bool fast = __all(c0.fast & c1.fast & c2.fast & c3.fast);
            if (fast) {
                stage_fast(vb, c0, S0);
                stage_fast(vb, c1, S1);
                stage_fast(vb, c2, S2);
                stage_fast(vb, c3, S3);
            } else {
                stage_safe(vb, c0, S0);
                stage_safe(vb, c1, S1);
                stage_safe(vb, c2, S2);
                stage_safe(vb, c3, S3);
            }
            __builtin_amdgcn_sched_barrier(0);  // keep loads hoisted above consumes
            consume(S0, T, wsum, aR, aG, aB);
            consume(S1, T, wsum, aR, aG, aB);
            consume(S2, T, wsum, aR, aG, aB);
            consume(S3, T, wsum, aR, aG, aB);
            if (!__any(T >= TAU)) break;
        }

        float scale = (1.0f - T) / (wsum + 1e-6f) * (1.0f / 255.0f);
        int po = y * W_RES + x;
        float* ob = out + (long long)b * 3 * NPIX;
        ob[po] = aR * scale;
        ob[po + NPIX] = aG * scale;
        ob[po + 2 * NPIX] = aB * scale;
    }
}

}  // namespace

extern "C" void kernel_launch(void* const* d_in, const int* in_sizes, int n_in,
                              void* d_out, int out_size, void* d_ws, size_t ws_size,
                              hipStream_t stream) {
    const float* vol = (const float*)d_in[0];  // (4,4,128,128,128) fp32
    const float* tfm = (const float*)d_in[1];  // (4,4,4) fp32
    float* out = (float*)d_out;                // (4,3,240,320) fp32

    unsigned char* ws = (unsigned char*)d_ws;
    uint4* v8 = (uint4*)ws;                          // u8x4 volume, 33.5 MB
    unsigned* ctr = (unsigned*)(ws + CTR_OFF);       // work-queue counter
    (void)ws_size; (void)in_sizes; (void)n_in; (void)out_size;

    const long long nq = (long long)BS * VOX / 4;    // 2,097,152 voxel-quads
    transpose_k<<<(int)((nq + 255) / 256), 256, 0, stream>>>(vol, v8, ctr);

    raycast_k<<<2048, 64, 0, stream>>>((const unsigned*)v8, tfm, out, ctr);
}

// Round 6
// 148.481 us; speedup vs baseline: 1.3573x; 1.3573x over previous
//
#include <hip/hip_runtime.h>

namespace {

constexpr int W_RES = 320, H_RES = 240, BS = 4, VD = 128, NS = 256;
constexpr float DENS_SCALE = 100.0f / 256.0f / 255.0f;  // u8 units -> ds
constexpr float TAU = 5e-4f;   // early-exit transmittance
constexpr long long VOX = (long long)VD * VD * VD;  // 2,097,152

// Transpose (B,4,D,H,W) fp32 -> (B,D,H,W) of uint2 entries:
// entry[x] = (u8x4 voxel[x], u8x4 voxel[x+1]), voxel[128] == 0 pad.
// One thread produces 2 entries (one uint4 store).
__global__ void transpose_k(const float* __restrict__ vol, uint4* __restrict__ out) {
    long long tid = (long long)blockIdx.x * blockDim.x + threadIdx.x;
    const long long npair = (long long)BS * VOX / 2;
    if (tid >= npair) return;
    int b = (int)(tid / (VOX / 2));
    long long r = (tid - (long long)b * (VOX / 2)) * 2;  // even entry index
    int x = (int)(r & (VD - 1));
    bool last = (x == VD - 2);  // x+2 would cross the row
    const float* vb = vol + (long long)b * 4 * VOX + r;
    float2 R = *(const float2*)(vb);
    float2 G = *(const float2*)(vb + VOX);
    float2 Bl = *(const float2*)(vb + 2 * VOX);
    float2 Dn = *(const float2*)(vb + 3 * VOX);
    float R2 = last ? 0.0f : vb[2];
    float G2 = last ? 0.0f : vb[VOX + 2];
    float B2 = last ? 0.0f : vb[2 * VOX + 2];
    float D2 = last ? 0.0f : vb[3 * VOX + 2];
    auto pk = [](float r_, float g_, float bl_, float d_) -> unsigned {
        unsigned ur = (unsigned)(r_ * 255.0f + 0.5f);
        unsigned ug = (unsigned)(g_ * 255.0f + 0.5f);
        unsigned ub = (unsigned)(bl_ * 255.0f + 0.5f);
        unsigned ud = (unsigned)(d_ * 255.0f + 0.5f);
        return ur | (ug << 8) | (ub << 16) | (ud << 24);
    };
    unsigned p0 = pk(R.x, G.x, Bl.x, Dn.x);
    unsigned p1 = pk(R.y, G.y, Bl.y, Dn.y);
    unsigned p2 = pk(R2, G2, B2, D2);  // zero when last
    uint4 o;
    o.x = p0; o.y = p1;   // entry r   = (v[x],   v[x+1])
    o.z = p1; o.w = p2;   // entry r+1 = (v[x+1], v[x+2] or pad)
    out[tid] = o;
}

struct St {
    uint2 p[4];    // 4 corner-pairs: (z0,y0) (z0,y1) (z1,y0) (z1,y1)
    float wzy[4];
    float wlo, whi;
};

struct Coord {
    int x0, y0, z0;
    float fx, fy, fz;
    bool fast;
};

__device__ __forceinline__ Coord mkc(float ix, float iy, float iz) {
    Coord c;
    float f;
    f = floorf(ix); c.fx = ix - f; c.x0 = (int)f;
    f = floorf(iy); c.fy = iy - f; c.y0 = (int)f;
    f = floorf(iz); c.fz = iz - f; c.z0 = (int)f;
    // x pad handles x0==127; y/z need headroom for the +VD / +VD*VD loads.
    c.fast = ((unsigned)c.x0 < 128u) & ((unsigned)c.y0 < 127u) & ((unsigned)c.z0 < 127u);
    return c;
}

__device__ __forceinline__ void stage_fast(const uint2* __restrict__ vb,
                                           const Coord& c, St& st) {
    const uint2* r0 = vb + ((c.z0 * VD + c.y0) * VD + c.x0);
    const uint2* r1 = r0 + VD * VD;
    st.p[0] = r0[0];
    st.p[1] = r0[VD];
    st.p[2] = r1[0];
    st.p[3] = r1[VD];
    st.wlo = 1.0f - c.fx;
    st.whi = c.fx;
    float wy0 = 1.0f - c.fy, wy1 = c.fy;
    float wz0 = 1.0f - c.fz, wz1 = c.fz;
    st.wzy[0] = wz0 * wy0; st.wzy[1] = wz0 * wy1;
    st.wzy[2] = wz1 * wy0; st.wzy[3] = wz1 * wy1;
}

__device__ __forceinline__ void stage_safe(const uint2* __restrict__ vb,
                                           const Coord& c, St& st) {
    int x0 = c.x0, y0 = c.y0, z0 = c.z0;
    bool in01x = ((unsigned)x0 < 128u);
    bool ism1 = (x0 == -1);
    st.wlo = in01x ? (1.0f - c.fx) : (ism1 ? c.fx : 0.0f);
    st.whi = in01x ? c.fx : 0.0f;
    int bx = min(max(x0, 0), 127);

    float my0 = ((unsigned)y0 < 128u) ? 1.0f : 0.0f;
    float my1 = ((unsigned)(y0 + 1) < 128u) ? 1.0f : 0.0f;
    float mz0 = ((unsigned)z0 < 128u) ? 1.0f : 0.0f;
    float mz1 = ((unsigned)(z0 + 1) < 128u) ? 1.0f : 0.0f;
    int yc0 = min(max(y0, 0), 127), yc1 = min(max(y0 + 1, 0), 127);
    int zc0 = min(max(z0, 0), 127), zc1 = min(max(z0 + 1, 0), 127);

    st.p[0] = vb[(zc0 * VD + yc0) * VD + bx];
    st.p[1] = vb[(zc0 * VD + yc1) * VD + bx];
    st.p[2] = vb[(zc1 * VD + yc0) * VD + bx];
    st.p[3] = vb[(zc1 * VD + yc1) * VD + bx];

    float wy0 = (1.0f - c.fy) * my0, wy1 = c.fy * my1;
    float wz0 = (1.0f - c.fz) * mz0, wz1 = c.fz * mz1;
    st.wzy[0] = wz0 * wy0; st.wzy[1] = wz0 * wy1;
    st.wzy[2] = wz1 * wy0; st.wzy[3] = wz1 * wy1;
}

__device__ __forceinline__ void consume(const St& st, float& T, float& wsum,
                                        float& aR, float& aG, float& aB) {
    float ar = 0, ag = 0, ab = 0, ad = 0;
#pragma unroll
    for (int i = 0; i < 4; ++i) {
        unsigned lo = st.p[i].x, hi = st.p[i].y;
        float wl = st.wzy[i] * st.wlo;
        float wh = st.wzy[i] * st.whi;
        ar = fmaf(wl, (float)(lo & 255u), ar);
        ag = fmaf(wl, (float)((lo >> 8) & 255u), ag);
        ab = fmaf(wl, (float)((lo >> 16) & 255u), ab);
        ad = fmaf(wl, (float)(lo >> 24), ad);
        ar = fmaf(wh, (float)(hi & 255u), ar);
        ag = fmaf(wh, (float)((hi >> 8) & 255u), ag);
        ab = fmaf(wh, (float)((hi >> 16) & 255u), ab);
        ad = fmaf(wh, (float)(hi >> 24), ad);
    }
    float dsv = ad * DENS_SCALE;
    T *= (1.0f - dsv);
    float wgt = dsv * T;
    wsum += wgt;
    aR = fmaf(wgt, ar, aR);
    aG = fmaf(wgt, ag, aG);
    aB = fmaf(wgt, ab, aB);
}

__global__ void __launch_bounds__(256) raycast_k(const uint2* __restrict__ vol,
                                                 const float* __restrict__ tfm,
                                                 float* __restrict__ out) {
    constexpr int NPIX = W_RES * H_RES;
    int lane = threadIdx.x & 63;
    int wave = threadIdx.x >> 6;
    // block covers a 16x16 pixel region; each wave a 16x4 strip
    int bx = blockIdx.x % (W_RES / 16);
    int rest = blockIdx.x / (W_RES / 16);
    int by = rest % (H_RES / 16);
    int b = rest / (H_RES / 16);
    int x = bx * 16 + (lane & 15);
    int y = by * 16 + wave * 4 + (lane >> 4);

    float X = -1.0f + 2.0f * x / (float)(W_RES - 1);
    float Y = -1.0f + 2.0f * y / (float)(H_RES - 1);
    const float dZ = 2.0f / (float)(NS - 1);

    const float* M = tfm + b * 16;
    float bxc = M[0] * X + M[1] * Y + M[3];
    float byc = M[4] * X + M[5] * Y + M[7];
    float bzc = M[8] * X + M[9] * Y + M[11];
    float bwc = M[12] * X + M[13] * Y + M[15];
    float m02 = M[2], m12 = M[6], m22 = M[10], m32 = M[14];

    const uint2* vb = vol + (long long)b * VOX;

    // Ray-box clip (exact when w row trivial; guarded for generality).
    bool w1 = (fabsf(bwc - 1.0f) < 1e-6f) && (fabsf(m32) < 1e-6f);
    float lo = 0.0f, hi = (float)(NS - 1);
    if (w1) {
        const float LIM = 1.0078125f + 1e-5f;  // some corner valid <=> |g| < 64.5/64
        auto clipAxis = [&](float bb, float mm) {
            float A = bb - mm;  // g(s) = A + B*s
            float Bq = mm * dZ;
            if (fabsf(Bq) < 1e-9f) {
                if (fabsf(A) > LIM) { lo = 1.0f; hi = 0.0f; }
            } else {
                float s1 = (-LIM - A) / Bq, s2 = (LIM - A) / Bq;
                lo = fmaxf(lo, fminf(s1, s2));
                hi = fminf(hi, fmaxf(s1, s2));
            }
        };
        clipAxis(bxc, m02);
        clipAxis(byc, m12);
        clipAxis(bzc, m22);
    }
    int s_start = max(0, (int)ceilf(lo - 1e-3f));
    int s_end = min(NS - 1, (int)floorf(hi + 1e-3f));

    // wave-common loop bounds
    int wsv = s_start, wev = s_end;
#pragma unroll
    for (int off = 1; off < 64; off <<= 1) {
        wsv = min(wsv, __shfl_xor(wsv, off));
        wev = max(wev, __shfl_xor(wev, off));
    }

    auto coords = [&](int s, float& ix, float& iy, float& iz) {
        float Z = fmaf((float)s, dZ, -1.0f);
        float gx = fmaf(m02, Z, bxc);
        float gy = fmaf(m12, Z, byc);
        float gz = fmaf(m22, Z, bzc);
        if (!w1) {
            float iw = 1.0f / fmaf(m32, Z, bwc);
            gx *= iw; gy *= iw; gz *= iw;
        }
        ix = fmaf(gx, 64.0f, 63.5f);
        iy = fmaf(gy, 64.0f, 63.5f);
        iz = fmaf(gz, 64.0f, 63.5f);
    };

    float T = 1.0f, wsum = 0.0f, aR = 0.0f, aG = 0.0f, aB = 0.0f;
    St S0, S1, S2;

    for (int s = wsv; s <= wev; s += 3) {
        bool alive = (T >= TAU);
        bool g0 = (s >= s_start) & (s <= s_end) & alive;
        bool g1 = (s + 1 >= s_start) & (s + 1 <= s_end) & alive;
        bool g2 = (s + 2 >= s_start) & (s + 2 <= s_end) & alive;
        Coord c0, c1, c2;
        float ix, iy, iz;
        if (g0) { coords(s, ix, iy, iz); c0 = mkc(ix, iy, iz); }
        if (g1) { coords(s + 1, ix, iy, iz); c1 = mkc(ix, iy, iz); }
        if (g2) { coords(s + 2, ix, iy, iz); c2 = mkc(ix, iy, iz); }
        bool fastAll = __all((g0 ? c0.fast : true) & (g1 ? c1.fast : true) &
                             (g2 ? c2.fast : true));
        if (fastAll) {
            if (g0) stage_fast(vb, c0, S0);
            if (g1) stage_fast(vb, c1, S1);
            if (g2) stage_fast(vb, c2, S2);
        } else {
            if (g0) stage_safe(vb, c0, S0);
            if (g1) stage_safe(vb, c1, S1);
            if (g2) stage_safe(vb, c2, S2);
        }
        __builtin_amdgcn_sched_barrier(0);  // keep loads hoisted above consumes
        if (g0) consume(S0, T, wsum, aR, aG, aB);
        if (g1 & (T >= TAU)) consume(S1, T, wsum, aR, aG, aB);
        if (g2 & (T >= TAU)) consume(S2, T, wsum, aR, aG, aB);
        if (!__any((T >= TAU) & (s + 3 <= s_end))) break;
    }

    float scale = (1.0f - T) / (wsum + 1e-6f) * (1.0f / 255.0f);
    int po = y * W_RES + x;
    float* ob = out + (long long)b * 3 * NPIX;
    ob[po] = aR * scale;
    ob[po + NPIX] = aG * scale;
    ob[po + 2 * NPIX] = aB * scale;
}

}  // namespace

extern "C" void kernel_launch(void* const* d_in, const int* in_sizes, int n_in,
                              void* d_out, int out_size, void* d_ws, size_t ws_size,
                              hipStream_t stream) {
    const float* vol = (const float*)d_in[0];  // (4,4,128,128,128) fp32
    const float* tfm = (const float*)d_in[1];  // (4,4,4) fp32
    float* out = (float*)d_out;                // (4,3,240,320) fp32

    uint4* v8 = (uint4*)d_ws;  // x-pair u8x4 volume, 67 MB
    (void)ws_size; (void)in_sizes; (void)n_in; (void)out_size;

    const long long npair = (long long)BS * VOX / 2;  // 4,194,304
    transpose_k<<<(int)((npair + 255) / 256), 256, 0, stream>>>(vol, v8);

    const int nblk = (W_RES / 16) * (H_RES / 16) * BS;  // 1200 blocks, 4800 waves
    raycast_k<<<nblk, 256, 0, stream>>>((const uint2*)v8, tfm, out);
}